// Round 1
// baseline (849.586 us; speedup 1.0000x reference)
//
#include <hip/hip_runtime.h>

typedef __bf16 bf16x8 __attribute__((ext_vector_type(8)));
typedef float f32x4 __attribute__((ext_vector_type(4)));
typedef unsigned short us8 __attribute__((ext_vector_type(8)));

#define B_ 64
#define T_ 1024
#define N_ 1024

__device__ __forceinline__ unsigned short f2bf(float f) {
  unsigned int u = __float_as_uint(f);
  u += 0x7fffu + ((u >> 16) & 1u);   // round-to-nearest-even
  return (unsigned short)(u >> 16);
}

__device__ __forceinline__ float fast_tanh(float x) {
  float xc = fminf(fmaxf(x, -15.f), 15.f);
  float e = __expf(2.f * xc);
  return (e - 1.f) / (e + 1.f);
}

// ---- Kernel 1: convert W_h (fp32 [N,N]) -> bf16 bits in ws ----
__global__ __launch_bounds__(256) void k_cvt_wh(const float* __restrict__ W_h,
                                                unsigned short* __restrict__ whb) {
  int i = (blockIdx.x * 256 + threadIdx.x) * 4;
  float4 x = *(const float4*)(W_h + i);
  ushort4 o;
  o.x = f2bf(x.x); o.y = f2bf(x.y); o.z = f2bf(x.z); o.w = f2bf(x.w);
  *(ushort4*)(whb + i) = o;
}

// ---- Kernel 2: dec_fea[b,m] = s_t_hat[b,:] . dec_W[m,:] + dec_b[m]; also zero scores ----
__global__ __launch_bounds__(256) void k_decfea(const float* __restrict__ s_t_hat,
                                                const float* __restrict__ dec_W,
                                                const float* __restrict__ dec_b,
                                                float* __restrict__ dec_fea,
                                                float* __restrict__ scores) {
  const int b = blockIdx.y;
  const int m = blockIdx.x * 256 + threadIdx.x;
  // zero the scores buffer (grid covers exactly B*T threads)
  int gid = (blockIdx.y * gridDim.x + blockIdx.x) * 256 + threadIdx.x;
  scores[gid] = 0.f;

  __shared__ float sh[N_];
  for (int i = threadIdx.x; i < N_; i += 256) sh[i] = s_t_hat[b * N_ + i];
  __syncthreads();

  float acc = dec_b[m];
  const float* w = dec_W + (size_t)m * N_;
  for (int k = 0; k < N_; k += 4) {
    float4 wv = *(const float4*)(w + k);
    acc += sh[k] * wv.x + sh[k + 1] * wv.y + sh[k + 2] * wv.z + sh[k + 3] * wv.w;
  }
  dec_fea[b * N_ + m] = acc;
}

// ---- Kernel 3: fused  S = h @ W_h^T ; scores[b,t] += sum_m tanh(S + dec_fea + cov*W_c) * v[m] ----
// 128x128 tile, 4 waves (2x2), each wave 4x4 subtiles of 16x16x32 MFMA, BK=32.
__global__ __launch_bounds__(256) void k_score(
    const float* __restrict__ h, const unsigned short* __restrict__ whb,
    const float* __restrict__ dec_fea, const float* __restrict__ coverage,
    const float* __restrict__ W_c, const float* __restrict__ v,
    float* __restrict__ scores) {
  __shared__ __align__(16) unsigned short lsA[128 * 40];  // [t_row][k], pad 40
  __shared__ __align__(16) unsigned short lsB[128 * 40];  // [m_row][k], pad 40

  const int tid = threadIdx.x;
  const int b = blockIdx.z;
  const int t0 = blockIdx.y * 128;
  const int m0 = blockIdx.x * 128;
  const int wave = tid >> 6, lane = tid & 63;
  const int wr = wave >> 1, wc = wave & 1;
  const int lm = lane & 15, lq = lane >> 4;

  f32x4 zero = {0.f, 0.f, 0.f, 0.f};
  f32x4 acc[4][4];
#pragma unroll
  for (int i = 0; i < 4; i++)
#pragma unroll
    for (int j = 0; j < 4; j++) acc[i][j] = zero;

  const float* hA = h + ((size_t)b * T_ + t0) * N_;
  const unsigned short* wB = whb + (size_t)m0 * N_;

  for (int k0 = 0; k0 < N_; k0 += 32) {
    __syncthreads();
    // stage A: h fp32 -> bf16, 128 rows x 32 k (512 slots of 8 elems, 2 iters)
    for (int s = tid; s < 512; s += 256) {
      int row = s >> 2, kc = (s & 3) * 8;
      const float* src = hA + (size_t)row * N_ + k0 + kc;
      float4 x = *(const float4*)src;
      float4 y = *(const float4*)(src + 4);
      unsigned short* d = &lsA[row * 40 + kc];
      d[0] = f2bf(x.x); d[1] = f2bf(x.y); d[2] = f2bf(x.z); d[3] = f2bf(x.w);
      d[4] = f2bf(y.x); d[5] = f2bf(y.y); d[6] = f2bf(y.z); d[7] = f2bf(y.w);
    }
    // stage B: pre-converted bf16 W_h rows (m = B-col), 16B vector copies
    for (int s = tid; s < 512; s += 256) {
      int row = s >> 2, kc = (s & 3) * 8;
      us8 x = *(const us8*)(wB + (size_t)row * N_ + k0 + kc);
      *(us8*)&lsB[row * 40 + kc] = x;
    }
    __syncthreads();

    bf16x8 af[4], bfr[4];
#pragma unroll
    for (int i = 0; i < 4; i++)
      af[i] = __builtin_bit_cast(bf16x8, *(const us8*)&lsA[(wr * 64 + i * 16 + lm) * 40 + lq * 8]);
#pragma unroll
    for (int j = 0; j < 4; j++)
      bfr[j] = __builtin_bit_cast(bf16x8, *(const us8*)&lsB[(wc * 64 + j * 16 + lm) * 40 + lq * 8]);
#pragma unroll
    for (int i = 0; i < 4; i++)
#pragma unroll
      for (int j = 0; j < 4; j++)
        acc[i][j] = __builtin_amdgcn_mfma_f32_16x16x32_bf16(af[i], bfr[j], acc[i][j], 0, 0, 0);
  }

  // epilogue: att = S + dec_fea[m] + cov[t]*W_c[m]; score partial = sum_m tanh(att)*v[m]
  float dfv[4], wcv[4], vv[4];
#pragma unroll
  for (int j = 0; j < 4; j++) {
    int m = m0 + wc * 64 + j * 16 + lm;   // D col = lane&15
    dfv[j] = dec_fea[b * N_ + m];
    wcv[j] = W_c[m];
    vv[j] = v[m];
  }
#pragma unroll
  for (int i = 0; i < 4; i++) {
#pragma unroll
    for (int r = 0; r < 4; r++) {
      int t = t0 + wr * 64 + i * 16 + lq * 4 + r;  // D row = quad*4 + reg
      float cv = coverage[b * T_ + t];
      float s = 0.f;
#pragma unroll
      for (int j = 0; j < 4; j++) {
        float x = acc[i][j][r] + dfv[j] + cv * wcv[j];
        s += fast_tanh(x) * vv[j];
      }
      // reduce across the 16 lanes (cols) sharing this t
      s += __shfl_xor(s, 1);
      s += __shfl_xor(s, 2);
      s += __shfl_xor(s, 4);
      s += __shfl_xor(s, 8);
      if (lm == 0) atomicAdd(&scores[b * T_ + t], s);
    }
  }
}

// ---- Kernel 4: softmax over t, mask, renormalize; write attn + coverage_new ----
__global__ __launch_bounds__(256) void k_softmax(const float* __restrict__ scores,
                                                 const float* __restrict__ mask,
                                                 const float* __restrict__ coverage,
                                                 float* __restrict__ attn_out,
                                                 float* __restrict__ cov_out) {
  const int b = blockIdx.x, tid = threadIdx.x;
  const int wave = tid >> 6, lane = tid & 63;
  const float* s = scores + b * T_;

  float vals[4];
  float lmax = -1e30f;
#pragma unroll
  for (int i = 0; i < 4; i++) {
    vals[i] = s[i * 256 + tid];
    lmax = fmaxf(lmax, vals[i]);
  }
#pragma unroll
  for (int off = 1; off < 64; off <<= 1) lmax = fmaxf(lmax, __shfl_xor(lmax, off));
  __shared__ float rmax[4], rsum[4];
  if (lane == 0) rmax[wave] = lmax;
  __syncthreads();
  float bmax = fmaxf(fmaxf(rmax[0], rmax[1]), fmaxf(rmax[2], rmax[3]));

  float w[4];
  float lsum = 0.f;
#pragma unroll
  for (int i = 0; i < 4; i++) {
    float e = __expf(vals[i] - bmax) * mask[b * T_ + i * 256 + tid];
    w[i] = e;
    lsum += e;
  }
#pragma unroll
  for (int off = 1; off < 64; off <<= 1) lsum += __shfl_xor(lsum, off);
  if (lane == 0) rsum[wave] = lsum;
  __syncthreads();
  float inv = 1.f / (rsum[0] + rsum[1] + rsum[2] + rsum[3]);

#pragma unroll
  for (int i = 0; i < 4; i++) {
    int t = i * 256 + tid;
    float a = w[i] * inv;
    attn_out[b * T_ + t] = a;
    cov_out[b * T_ + t] = coverage[b * T_ + t] + a;
  }
}

// ---- Kernel 5: c_t[b,n] = sum_t attn[b,t] * h[b,t,n] ----
__global__ __launch_bounds__(256) void k_ctx(const float* __restrict__ h,
                                             const float* __restrict__ attn,
                                             float* __restrict__ c_t) {
  const int b = blockIdx.y;
  const int n = blockIdx.x * 256 + threadIdx.x;
  __shared__ float la[T_];
  for (int i = threadIdx.x; i < T_; i += 256) la[i] = attn[b * T_ + i];
  __syncthreads();
  const float* hb = h + (size_t)b * T_ * N_ + n;
  float acc = 0.f;
#pragma unroll 8
  for (int t = 0; t < T_; t++) acc += la[t] * hb[(size_t)t * N_];
  c_t[b * N_ + n] = acc;
}

extern "C" void kernel_launch(void* const* d_in, const int* in_sizes, int n_in,
                              void* d_out, int out_size, void* d_ws, size_t ws_size,
                              hipStream_t stream) {
  const float* s_t_hat  = (const float*)d_in[0];
  const float* h        = (const float*)d_in[1];
  const float* mask     = (const float*)d_in[2];
  const float* coverage = (const float*)d_in[3];
  const float* W_h      = (const float*)d_in[4];
  const float* W_c      = (const float*)d_in[5];
  const float* dec_W    = (const float*)d_in[6];
  const float* dec_b    = (const float*)d_in[7];
  const float* v        = (const float*)d_in[8];

  float* out = (float*)d_out;
  float* out_ct   = out;                 // [B,N]
  float* out_attn = out + B_ * T_;       // [B,T]
  float* out_cov  = out + 2 * B_ * T_;   // [B,T]

  char* ws = (char*)d_ws;
  unsigned short* whb = (unsigned short*)ws;                       // 2 MB bf16 W_h
  float* dec_fea = (float*)(ws + (size_t)2 * 1024 * 1024);         // 256 KB
  float* scores  = (float*)(ws + (size_t)2 * 1024 * 1024 + 256 * 1024);  // 256 KB

  k_cvt_wh<<<dim3(N_ * N_ / 1024), 256, 0, stream>>>(W_h, whb);
  k_decfea<<<dim3(4, B_), 256, 0, stream>>>(s_t_hat, dec_W, dec_b, dec_fea, scores);
  k_score<<<dim3(N_ / 128, T_ / 128, B_), 256, 0, stream>>>(h, whb, dec_fea, coverage, W_c, v, scores);
  k_softmax<<<dim3(B_), 256, 0, stream>>>(scores, mask, coverage, out_attn, out_cov);
  k_ctx<<<dim3(4, B_), 256, 0, stream>>>(h, out_attn, out_ct);
}

// Round 2
// 661.677 us; speedup vs baseline: 1.2840x; 1.2840x over previous
//
#include <hip/hip_runtime.h>

typedef __bf16 bf16x8 __attribute__((ext_vector_type(8)));
typedef float f32x4 __attribute__((ext_vector_type(4)));
typedef unsigned short us8 __attribute__((ext_vector_type(8)));

#define B_ 64
#define T_ 1024
#define N_ 1024

__device__ __forceinline__ unsigned short f2bf(float f) {
  unsigned int u = __float_as_uint(f);
  u += 0x7fffu + ((u >> 16) & 1u);   // round-to-nearest-even
  return (unsigned short)(u >> 16);
}

__device__ __forceinline__ float fast_tanh(float x) {
  float xc = fminf(fmaxf(x, -15.f), 15.f);
  float e = __expf(2.f * xc);
  return (e - 1.f) / (e + 1.f);
}

// async global->LDS, 16B per lane. LDS dest must be wave-uniform base + lane*16.
__device__ __forceinline__ void async16(const unsigned short* g, unsigned short* l) {
  __builtin_amdgcn_global_load_lds((const __attribute__((address_space(1))) void*)g,
                                   (__attribute__((address_space(3))) void*)l, 16, 0, 0);
}

// ---- Kernel 1: convert W_h -> bf16; also zero scores and c_t accumulators ----
__global__ __launch_bounds__(256) void k_cvt_wh(const float* __restrict__ W_h,
                                                unsigned short* __restrict__ whb,
                                                float* __restrict__ scores,
                                                float* __restrict__ ct) {
  int base = blockIdx.x * 256 + threadIdx.x;          // grid = 1024 blocks -> 262144 threads
  size_t i = (size_t)base * 4;
  float4 x = *(const float4*)(W_h + i);
  ushort4 o;
  o.x = f2bf(x.x); o.y = f2bf(x.y); o.z = f2bf(x.z); o.w = f2bf(x.w);
  *(ushort4*)(whb + i) = o;
  if (base < B_ * T_) scores[base] = 0.f;
  if (base < B_ * N_) ct[base] = 0.f;
}

// ---- Kernel 1b: convert h (fp32 [B,T,N]) -> bf16 in ws ----
__global__ __launch_bounds__(256) void k_cvt_h(const float* __restrict__ h,
                                               unsigned short* __restrict__ hbf) {
  size_t i = ((size_t)blockIdx.x * 256 + threadIdx.x) * 8;
  float4 x = *(const float4*)(h + i);
  float4 y = *(const float4*)(h + i + 4);
  us8 o;
  o[0] = f2bf(x.x); o[1] = f2bf(x.y); o[2] = f2bf(x.z); o[3] = f2bf(x.w);
  o[4] = f2bf(y.x); o[5] = f2bf(y.y); o[6] = f2bf(y.z); o[7] = f2bf(y.w);
  *(us8*)(hbf + i) = o;
}

// ---- Kernel 2: dec_fea[b,m] = s_t_hat[b,:] . dec_W[m,:] + dec_b[m] ----
// block = 64 m-rows x 8 batches; dec_W streamed once per 8 batches (8x total).
__global__ __launch_bounds__(256) void k_decfea2(const float* __restrict__ s_t_hat,
                                                 const float* __restrict__ dec_W,
                                                 const float* __restrict__ dec_b,
                                                 float* __restrict__ dec_fea) {
  const int m0 = blockIdx.x * 64;
  const int bg0 = blockIdx.y * 8;
  __shared__ float sh[8][N_];       // 32 KB
  __shared__ float red[4][64][8];   // 8 KB
  const int tid = threadIdx.x;
  for (int idx = tid; idx < 8 * N_; idx += 256) {
    int bb = idx >> 10, k = idx & (N_ - 1);
    sh[bb][k] = s_t_hat[(size_t)(bg0 + bb) * N_ + k];
  }
  __syncthreads();
  const int tm = tid >> 2;      // 0..63
  const int seg = tid & 3;      // interleaved k: k = seg*4 + 16*i  (bank-conflict-free)
  const float* w = dec_W + (size_t)(m0 + tm) * N_;
  float acc[8];
#pragma unroll
  for (int bb = 0; bb < 8; bb++) acc[bb] = 0.f;
  for (int i = 0; i < 64; i++) {
    int k = seg * 4 + i * 16;
    float4 wv = *(const float4*)(w + k);
#pragma unroll
    for (int bb = 0; bb < 8; bb++)
      acc[bb] += sh[bb][k] * wv.x + sh[bb][k + 1] * wv.y + sh[bb][k + 2] * wv.z + sh[bb][k + 3] * wv.w;
  }
#pragma unroll
  for (int bb = 0; bb < 8; bb++) red[seg][tm][bb] = acc[bb];
  __syncthreads();
  int om = tid & 63, ob = tid >> 6;
#pragma unroll
  for (int p = 0; p < 2; p++) {
    int obb = ob + p * 4;
    float s = red[0][om][obb] + red[1][om][obb] + red[2][om][obb] + red[3][om][obb] + dec_b[m0 + om];
    dec_fea[(size_t)(bg0 + obb) * N_ + m0 + om] = s;
  }
}

// ---- Kernel 3 (main path): fused scores via MFMA with global_load_lds staging ----
// m97 structure: 128x128 tile, BK=32, unpadded 64B LDS rows + XOR chunk swizzle.
__global__ __launch_bounds__(256) void k_score2(
    const unsigned short* __restrict__ hbf, const unsigned short* __restrict__ whb,
    const float* __restrict__ dec_fea, const float* __restrict__ coverage,
    const float* __restrict__ W_c, const float* __restrict__ v,
    float* __restrict__ scores) {
  __shared__ __align__(16) unsigned short lsA[128 * 32];  // 8 KB
  __shared__ __align__(16) unsigned short lsB[128 * 32];  // 8 KB

  const int tid = threadIdx.x;
  const int b = blockIdx.z;
  const int t0 = blockIdx.y * 128;
  const int m0 = blockIdx.x * 128;
  const int wave = tid >> 6, lane = tid & 63;
  const int wr = wave >> 1, wc = wave & 1;
  const int lm = lane & 15, lq = lane >> 4;

  f32x4 acc[4][4];
#pragma unroll
  for (int i = 0; i < 4; i++)
#pragma unroll
    for (int j = 0; j < 4; j++) acc[i][j] = (f32x4){0.f, 0.f, 0.f, 0.f};

  // staging: slot s in [0,512): row = s>>2, chunk c = s&3 holds global chunk c ^ key(row)
  const int r0 = tid >> 2;
  const int key0 = (r0 & 3) ^ ((r0 >> 2) & 3);     // same key for r0 and r0+64
  const int cc = ((tid & 3) ^ key0) * 8;           // element offset of staged global chunk
  const unsigned short* gA = hbf + ((size_t)(b * T_ + t0)) * N_;
  const unsigned short* gB = whb + (size_t)m0 * N_;
  const size_t ga0 = (size_t)r0 * N_ + cc;
  const size_t ga1 = (size_t)(r0 + 64) * N_ + cc;
  unsigned short* la0 = &lsA[tid * 8];
  unsigned short* la1 = &lsA[(tid + 256) * 8];
  unsigned short* lb0 = &lsB[tid * 8];
  unsigned short* lb1 = &lsB[(tid + 256) * 8];

  // ds_read swizzle: row key depends only on lm
  const int keyL = (lm & 3) ^ ((lm >> 2) & 3);
  const int rdoff = (lq ^ keyL) * 8;

  for (int k0 = 0; k0 < N_; k0 += 32) {
    async16(gA + ga0 + k0, la0);
    async16(gA + ga1 + k0, la1);
    async16(gB + ga0 + k0, lb0);
    async16(gB + ga1 + k0, lb1);
    __syncthreads();   // drains vmcnt -> staged data visible

    bf16x8 af[4], bfr[4];
#pragma unroll
    for (int i = 0; i < 4; i++)
      af[i] = __builtin_bit_cast(bf16x8, *(const us8*)&lsA[(wr * 64 + i * 16 + lm) * 32 + rdoff]);
#pragma unroll
    for (int j = 0; j < 4; j++)
      bfr[j] = __builtin_bit_cast(bf16x8, *(const us8*)&lsB[(wc * 64 + j * 16 + lm) * 32 + rdoff]);
#pragma unroll
    for (int i = 0; i < 4; i++)
#pragma unroll
      for (int j = 0; j < 4; j++)
        acc[i][j] = __builtin_amdgcn_mfma_f32_16x16x32_bf16(af[i], bfr[j], acc[i][j], 0, 0, 0);
    __syncthreads();   // LDS safe to overwrite next iter
  }

  // epilogue: scores[b,t] += sum_m tanh(S + dec_fea[m] + cov[t]*W_c[m]) * v[m]
  float dfv[4], wcv[4], vv[4];
#pragma unroll
  for (int j = 0; j < 4; j++) {
    int m = m0 + wc * 64 + j * 16 + lm;   // D col = lane&15
    dfv[j] = dec_fea[b * N_ + m];
    wcv[j] = W_c[m];
    vv[j] = v[m];
  }
#pragma unroll
  for (int i = 0; i < 4; i++) {
#pragma unroll
    for (int r = 0; r < 4; r++) {
      int t = t0 + wr * 64 + i * 16 + lq * 4 + r;  // D row = quad*4 + reg
      float cv = coverage[b * T_ + t];
      float s = 0.f;
#pragma unroll
      for (int j = 0; j < 4; j++) {
        float x = acc[i][j][r] + dfv[j] + cv * wcv[j];
        s += fast_tanh(x) * vv[j];
      }
      s += __shfl_xor(s, 1);
      s += __shfl_xor(s, 2);
      s += __shfl_xor(s, 4);
      s += __shfl_xor(s, 8);
      if (lm == 0) atomicAdd(&scores[b * T_ + t], s);
    }
  }
}

// ---- Kernel 3 (fallback, ws too small): round-1 version with fp32 h staging ----
__global__ __launch_bounds__(256) void k_score_fb(
    const float* __restrict__ h, const unsigned short* __restrict__ whb,
    const float* __restrict__ dec_fea, const float* __restrict__ coverage,
    const float* __restrict__ W_c, const float* __restrict__ v,
    float* __restrict__ scores) {
  __shared__ __align__(16) unsigned short lsA[128 * 40];
  __shared__ __align__(16) unsigned short lsB[128 * 40];
  const int tid = threadIdx.x;
  const int b = blockIdx.z;
  const int t0 = blockIdx.y * 128;
  const int m0 = blockIdx.x * 128;
  const int wave = tid >> 6, lane = tid & 63;
  const int wr = wave >> 1, wc = wave & 1;
  const int lm = lane & 15, lq = lane >> 4;
  f32x4 acc[4][4];
#pragma unroll
  for (int i = 0; i < 4; i++)
#pragma unroll
    for (int j = 0; j < 4; j++) acc[i][j] = (f32x4){0.f, 0.f, 0.f, 0.f};
  const float* hA = h + ((size_t)b * T_ + t0) * N_;
  const unsigned short* wB = whb + (size_t)m0 * N_;
  for (int k0 = 0; k0 < N_; k0 += 32) {
    __syncthreads();
    for (int s = tid; s < 512; s += 256) {
      int row = s >> 2, kc = (s & 3) * 8;
      const float* src = hA + (size_t)row * N_ + k0 + kc;
      float4 x = *(const float4*)src;
      float4 y = *(const float4*)(src + 4);
      unsigned short* d = &lsA[row * 40 + kc];
      d[0] = f2bf(x.x); d[1] = f2bf(x.y); d[2] = f2bf(x.z); d[3] = f2bf(x.w);
      d[4] = f2bf(y.x); d[5] = f2bf(y.y); d[6] = f2bf(y.z); d[7] = f2bf(y.w);
    }
    for (int s = tid; s < 512; s += 256) {
      int row = s >> 2, kc = (s & 3) * 8;
      us8 x = *(const us8*)(wB + (size_t)row * N_ + k0 + kc);
      *(us8*)&lsB[row * 40 + kc] = x;
    }
    __syncthreads();
    bf16x8 af[4], bfr[4];
#pragma unroll
    for (int i = 0; i < 4; i++)
      af[i] = __builtin_bit_cast(bf16x8, *(const us8*)&lsA[(wr * 64 + i * 16 + lm) * 40 + lq * 8]);
#pragma unroll
    for (int j = 0; j < 4; j++)
      bfr[j] = __builtin_bit_cast(bf16x8, *(const us8*)&lsB[(wc * 64 + j * 16 + lm) * 40 + lq * 8]);
#pragma unroll
    for (int i = 0; i < 4; i++)
#pragma unroll
      for (int j = 0; j < 4; j++)
        acc[i][j] = __builtin_amdgcn_mfma_f32_16x16x32_bf16(af[i], bfr[j], acc[i][j], 0, 0, 0);
  }
  float dfv[4], wcv[4], vv[4];
#pragma unroll
  for (int j = 0; j < 4; j++) {
    int m = m0 + wc * 64 + j * 16 + lm;
    dfv[j] = dec_fea[b * N_ + m];
    wcv[j] = W_c[m];
    vv[j] = v[m];
  }
#pragma unroll
  for (int i = 0; i < 4; i++) {
#pragma unroll
    for (int r = 0; r < 4; r++) {
      int t = t0 + wr * 64 + i * 16 + lq * 4 + r;
      float cv = coverage[b * T_ + t];
      float s = 0.f;
#pragma unroll
      for (int j = 0; j < 4; j++) {
        float x = acc[i][j][r] + dfv[j] + cv * wcv[j];
        s += fast_tanh(x) * vv[j];
      }
      s += __shfl_xor(s, 1);
      s += __shfl_xor(s, 2);
      s += __shfl_xor(s, 4);
      s += __shfl_xor(s, 8);
      if (lm == 0) atomicAdd(&scores[b * T_ + t], s);
    }
  }
}

// ---- Kernel 4: softmax over t, mask, renormalize; write attn + coverage_new ----
__global__ __launch_bounds__(256) void k_softmax(const float* __restrict__ scores,
                                                 const float* __restrict__ mask,
                                                 const float* __restrict__ coverage,
                                                 float* __restrict__ attn_out,
                                                 float* __restrict__ cov_out) {
  const int b = blockIdx.x, tid = threadIdx.x;
  const int wave = tid >> 6, lane = tid & 63;
  const float* s = scores + b * T_;
  float vals[4];
  float lmax = -1e30f;
#pragma unroll
  for (int i = 0; i < 4; i++) {
    vals[i] = s[i * 256 + tid];
    lmax = fmaxf(lmax, vals[i]);
  }
#pragma unroll
  for (int off = 1; off < 64; off <<= 1) lmax = fmaxf(lmax, __shfl_xor(lmax, off));
  __shared__ float rmax[4], rsum[4];
  if (lane == 0) rmax[wave] = lmax;
  __syncthreads();
  float bmax = fmaxf(fmaxf(rmax[0], rmax[1]), fmaxf(rmax[2], rmax[3]));
  float w[4];
  float lsum = 0.f;
#pragma unroll
  for (int i = 0; i < 4; i++) {
    float e = __expf(vals[i] - bmax) * mask[b * T_ + i * 256 + tid];
    w[i] = e;
    lsum += e;
  }
#pragma unroll
  for (int off = 1; off < 64; off <<= 1) lsum += __shfl_xor(lsum, off);
  if (lane == 0) rsum[wave] = lsum;
  __syncthreads();
  float inv = 1.f / (rsum[0] + rsum[1] + rsum[2] + rsum[3]);
#pragma unroll
  for (int i = 0; i < 4; i++) {
    int t = i * 256 + tid;
    float a = w[i] * inv;
    attn_out[b * T_ + t] = a;
    cov_out[b * T_ + t] = coverage[b * T_ + t] + a;
  }
}

// ---- Kernel 5 (main): c_t[b,n] += sum_t attn[b,t] * h_bf16[b,t,n], t-split + atomics ----
__global__ __launch_bounds__(256) void k_ctx2(const unsigned short* __restrict__ hbf,
                                              const float* __restrict__ attn,
                                              float* __restrict__ c_t) {
  const int b = blockIdx.z;
  const int t0 = blockIdx.y * 128;
  const int n0 = blockIdx.x * 512 + threadIdx.x * 2;
  __shared__ float la[128];
  if (threadIdx.x < 128) la[threadIdx.x] = attn[b * T_ + t0 + threadIdx.x];
  __syncthreads();
  const unsigned short* hp = hbf + ((size_t)(b * T_ + t0)) * N_ + n0;
  float a0 = 0.f, a1 = 0.f;
#pragma unroll 8
  for (int t = 0; t < 128; t++) {
    unsigned u = *(const unsigned*)(hp + (size_t)t * N_);
    float lo = __uint_as_float(u << 16);
    float hi = __uint_as_float(u & 0xffff0000u);
    float a = la[t];
    a0 += a * lo;
    a1 += a * hi;
  }
  atomicAdd(&c_t[b * N_ + n0], a0);
  atomicAdd(&c_t[b * N_ + n0 + 1], a1);
}

// ---- Kernel 5 (fallback): round-1 version ----
__global__ __launch_bounds__(256) void k_ctx_fb(const float* __restrict__ h,
                                                const float* __restrict__ attn,
                                                float* __restrict__ c_t) {
  const int b = blockIdx.y;
  const int n = blockIdx.x * 256 + threadIdx.x;
  __shared__ float la[T_];
  for (int i = threadIdx.x; i < T_; i += 256) la[i] = attn[b * T_ + i];
  __syncthreads();
  const float* hb = h + (size_t)b * T_ * N_ + n;
  float acc = 0.f;
#pragma unroll 8
  for (int t = 0; t < T_; t++) acc += la[t] * hb[(size_t)t * N_];
  c_t[b * N_ + n] = acc;
}

extern "C" void kernel_launch(void* const* d_in, const int* in_sizes, int n_in,
                              void* d_out, int out_size, void* d_ws, size_t ws_size,
                              hipStream_t stream) {
  const float* s_t_hat  = (const float*)d_in[0];
  const float* h        = (const float*)d_in[1];
  const float* mask     = (const float*)d_in[2];
  const float* coverage = (const float*)d_in[3];
  const float* W_h      = (const float*)d_in[4];
  const float* W_c      = (const float*)d_in[5];
  const float* dec_W    = (const float*)d_in[6];
  const float* dec_b    = (const float*)d_in[7];
  const float* v        = (const float*)d_in[8];

  float* out = (float*)d_out;
  float* out_ct   = out;                 // [B,N]
  float* out_attn = out + B_ * T_;       // [B,T]
  float* out_cov  = out + 2 * B_ * T_;   // [B,T]

  const size_t hbf_bytes = (size_t)B_ * T_ * N_ * 2;   // 128 MB
  const size_t whb_bytes = (size_t)N_ * N_ * 2;        // 2 MB
  const size_t df_bytes  = (size_t)B_ * N_ * 4;        // 256 KB
  const size_t sc_bytes  = (size_t)B_ * T_ * 4;        // 256 KB
  const bool big = ws_size >= hbf_bytes + whb_bytes + df_bytes + sc_bytes;

  char* ws = (char*)d_ws;
  if (big) {
    unsigned short* hbf = (unsigned short*)ws;
    unsigned short* whb = (unsigned short*)(ws + hbf_bytes);
    float* dec_fea = (float*)(ws + hbf_bytes + whb_bytes);
    float* scores  = (float*)(ws + hbf_bytes + whb_bytes + df_bytes);

    k_cvt_wh<<<dim3(N_ * N_ / 1024), 256, 0, stream>>>(W_h, whb, scores, out_ct);
    k_cvt_h<<<dim3(B_ * T_ * N_ / 2048), 256, 0, stream>>>(h, hbf);
    k_decfea2<<<dim3(16, 8), 256, 0, stream>>>(s_t_hat, dec_W, dec_b, dec_fea);
    k_score2<<<dim3(N_ / 128, T_ / 128, B_), 256, 0, stream>>>(hbf, whb, dec_fea, coverage, W_c, v, scores);
    k_softmax<<<dim3(B_), 256, 0, stream>>>(scores, mask, coverage, out_attn, out_cov);
    k_ctx2<<<dim3(2, 8, B_), 256, 0, stream>>>(hbf, out_attn, out_ct);
  } else {
    unsigned short* whb = (unsigned short*)ws;
    float* dec_fea = (float*)(ws + whb_bytes);
    float* scores  = (float*)(ws + whb_bytes + df_bytes);

    k_cvt_wh<<<dim3(N_ * N_ / 1024), 256, 0, stream>>>(W_h, whb, scores, out_ct);
    k_decfea2<<<dim3(16, 8), 256, 0, stream>>>(s_t_hat, dec_W, dec_b, dec_fea);
    k_score_fb<<<dim3(N_ / 128, T_ / 128, B_), 256, 0, stream>>>(h, whb, dec_fea, coverage, W_c, v, scores);
    k_softmax<<<dim3(B_), 256, 0, stream>>>(scores, mask, coverage, out_attn, out_cov);
    k_ctx_fb<<<dim3(4, B_), 256, 0, stream>>>(h, out_attn, out_ct);
  }
}